// Round 2
// baseline (9.974 us; speedup 1.0000x reference)
//
#include <hip/hip_runtime.h>

// TernaryQuantizer — analytic collapse (see round 0):
//   q_full == q_factored (729-codebook tensor-factorizes; softmax over
//   separable logits = product of per-dim softmaxes), gate irrelevant.
//   Per-scalar closed form, algebraically reduced:
//     u = e^{2x/T};  q = (u - 1/u) / (e^{1/T} + u + 1/u)
//     out = BLEND*q + (1-BLEND)*x,  T=0.3, BLEND=1/1.3
//   -> 1 v_exp_f32 + 2 v_rcp_f32 + ~5 FMAs per element.
// Elementwise over 786432 f32; ~6.3 MB traffic; latency/launch-bound regime,
// so: 256 blocks x 256 thr x 3 float4 (1024 waves = 1/SIMD), straight-line,
// all loads issued up-front.

#define TQ_BLEND 0.769230769f   // 1/1.3
#define TQ_KEEP  0.230769231f   // 1 - BLEND

__device__ __forceinline__ float tq_out(float x) {
    const float S = 9.617976939f;    // 2 / (T * ln2)
    const float C = 28.0316248f;     // e^{1/T}
    float xc = fminf(fmaxf(x, -12.0f), 12.0f);   // overflow guard (|x|<13.1 safe)
    float u  = __builtin_amdgcn_exp2f(xc * S);   // v_exp_f32
    float ru = __builtin_amdgcn_rcpf(u);         // v_rcp_f32
    float q  = (u - ru) * __builtin_amdgcn_rcpf(C + u + ru);
    return fmaf(TQ_BLEND, q, TQ_KEEP * x);
}

__device__ __forceinline__ float4 tq_out4(float4 v) {
    float4 r;
    r.x = tq_out(v.x);
    r.y = tq_out(v.y);
    r.z = tq_out(v.z);
    r.w = tq_out(v.w);
    return r;
}

// Exact-size fast path: n == 786432 -> 196608 float4s = 65536 threads x 3.
__global__ void __launch_bounds__(256)
tq_kernel_fast(const float4* __restrict__ x4, float4* __restrict__ out4) {
    const int tid = blockIdx.x * 256 + threadIdx.x;
    // issue all loads before any compute (MLP: one HBM latency, not three)
    float4 v0 = x4[tid];
    float4 v1 = x4[tid + 65536];
    float4 v2 = x4[tid + 131072];
    float4 r0 = tq_out4(v0);
    float4 r1 = tq_out4(v1);
    float4 r2 = tq_out4(v2);
    out4[tid]          = r0;
    out4[tid + 65536]  = r1;
    out4[tid + 131072] = r2;
}

// Generic fallback (any n), grid-stride float4 + scalar tail.
__global__ void __launch_bounds__(256)
tq_kernel_generic(const float* __restrict__ x, float* __restrict__ out, int n) {
    const int n4 = n >> 2;
    const int stride = gridDim.x * blockDim.x;
    for (int i = blockIdx.x * blockDim.x + threadIdx.x; i < n4; i += stride) {
        reinterpret_cast<float4*>(out)[i] =
            tq_out4(reinterpret_cast<const float4*>(x)[i]);
    }
    const int tid = blockIdx.x * blockDim.x + threadIdx.x;
    const int tail = n & 3;
    if (tid < tail) {
        const int idx = (n4 << 2) + tid;
        out[idx] = tq_out(x[idx]);
    }
}

extern "C" void kernel_launch(void* const* d_in, const int* in_sizes, int n_in,
                              void* d_out, int out_size, void* d_ws, size_t ws_size,
                              hipStream_t stream) {
    const float* x = (const float*)d_in[0];   // (16, 8192, 6) f32
    float* out = (float*)d_out;
    const int n = in_sizes[0];                // 786432 expected

    if (n == 786432) {
        tq_kernel_fast<<<256, 256, 0, stream>>>(
            reinterpret_cast<const float4*>(x), reinterpret_cast<float4*>(out));
    } else {
        const int block = 256;
        int n4 = (n + 3) >> 2;
        int grid = (n4 + block - 1) / block;
        if (grid < 1) grid = 1;
        if (grid > 2048) grid = 2048;
        tq_kernel_generic<<<grid, block, 0, stream>>>(x, out, n);
    }
}